// Round 11
// baseline (247.036 us; speedup 1.0000x reference)
//
#include <hip/hip_runtime.h>
#include <math.h>

#define NB 32
#define NN 512
#define ROWC 2048ull

typedef __attribute__((ext_vector_type(8))) short bf16x8;
typedef __attribute__((ext_vector_type(4))) float f32x4;

__device__ __forceinline__ unsigned int fbits(float f) {
  union { float f; unsigned int u; } v; v.f = f; return v.u;
}
__device__ __forceinline__ float bcast(unsigned int u) {
  union { unsigned int u; float f; } v; v.u = u; return v.f;
}
// round-to-nearest-even bf16, returned in low 16 bits
__device__ __forceinline__ unsigned int bf16_rne(float f) {
  unsigned int b = fbits(f);
  return (b + 0x7FFFu + ((b >> 16) & 1u)) >> 16;
}

// Fragment-ordered LDS address (BK=64 form) used by gemm_wp / gemm_wh.
__device__ __forceinline__ int frag_byte(int blk, int lane, int khalf) {
  int base = ((((khalf << 3) + blk) << 6) + lane) << 4;
  int swz = (blk ^ (lane >> 4) ^ (khalf << 2)) & 7;
  return base ^ (swz << 4);
}

// BK=32 form (khalf==0) of the same proven map.
__device__ __forceinline__ int frag32(int blk, int lane) {
  int base = (blk << 10) + (lane << 4);
  int swz = (blk ^ (lane >> 4)) & 7;
  return base ^ (swz << 4);
}

// --- Kernel 1: e = px.hx^T, 3-term split bf16 (r2-r9 formula, absmax 0.125),
// gemm_wp's exact skeleton: 256 threads, BK=32, 33.8KB LDS, 2-barrier k-loop.
// e ~= al.bh + ah.bl + ah.bh  (a = px truncated hi + exact residual lo; same
// for b = hx). 2-term (r10) failed: hx RNE error alone -> absmax 0.59.
__global__ __launch_bounds__(256) void gemm_e(
    const float* __restrict__ px, const float* __restrict__ hx,
    float* __restrict__ e) {
  __shared__ union {
    struct { char Ah[8192]; char Al[8192]; char Bh[8192]; char Bl[8192]; } s;
    float ep[64][132];
  } u;
  const int b = blockIdx.z;
  const float* A = px + (size_t)b * NN * NN;
  const float* B = hx + (size_t)b * NN * NN;
  float* C = e + (size_t)b * NN * NN;
  const int row0 = blockIdx.y * 128, col0 = blockIdx.x * 128;
  const int t = threadIdx.x;
  const int l = t & 63, w = t >> 6;
  const int wr = w >> 1, wc = w & 1;

  f32x4 acc[4][4];
#pragma unroll
  for (int i = 0; i < 4; ++i)
#pragma unroll
    for (int j = 0; j < 4; ++j)
#pragma unroll
      for (int r = 0; r < 4; ++r) acc[i][j][r] = 0.f;

  for (int k0 = 0; k0 < NN; k0 += 32) {
    // stage A: px -> truncated-hi + exact-residual-lo bf16
#pragma unroll
    for (int i = 0; i < 4; ++i) {
      int idx = i * 256 + t;
      int r = idx >> 3, c4 = idx & 7, k = c4 << 2;
      int byte = frag32(r >> 4, (r & 15) + ((c4 >> 1) << 4)) + (c4 & 1) * 8;
      float4 f = *(const float4*)&A[(size_t)(row0 + r) * NN + k0 + k];
      unsigned int b0 = fbits(f.x), b1 = fbits(f.y), b2 = fbits(f.z), b3 = fbits(f.w);
      unsigned int h01 = (b0 >> 16) | (b1 & 0xFFFF0000u);
      unsigned int h23 = (b2 >> 16) | (b3 & 0xFFFF0000u);
      float r0 = f.x - bcast(b0 & 0xFFFF0000u);
      float r1 = f.y - bcast(b1 & 0xFFFF0000u);
      float r2 = f.z - bcast(b2 & 0xFFFF0000u);
      float r3 = f.w - bcast(b3 & 0xFFFF0000u);
      unsigned int l01 = (fbits(r0) >> 16) | (fbits(r1) & 0xFFFF0000u);
      unsigned int l23 = (fbits(r2) >> 16) | (fbits(r3) & 0xFFFF0000u);
      *(uint2*)&u.s.Ah[byte] = make_uint2(h01, h23);
      *(uint2*)&u.s.Al[byte] = make_uint2(l01, l23);
    }
    // stage B: hx -> truncated-hi + exact-residual-lo bf16
#pragma unroll
    for (int i = 0; i < 4; ++i) {
      int idx = i * 256 + t;
      int r = idx >> 3, c4 = idx & 7, k = c4 << 2;
      int byte = frag32(r >> 4, (r & 15) + ((c4 >> 1) << 4)) + (c4 & 1) * 8;
      float4 f = *(const float4*)&B[(size_t)(col0 + r) * NN + k0 + k];
      unsigned int b0 = fbits(f.x), b1 = fbits(f.y), b2 = fbits(f.z), b3 = fbits(f.w);
      unsigned int h01 = (b0 >> 16) | (b1 & 0xFFFF0000u);
      unsigned int h23 = (b2 >> 16) | (b3 & 0xFFFF0000u);
      float r0 = f.x - bcast(b0 & 0xFFFF0000u);
      float r1 = f.y - bcast(b1 & 0xFFFF0000u);
      float r2 = f.z - bcast(b2 & 0xFFFF0000u);
      float r3 = f.w - bcast(b3 & 0xFFFF0000u);
      unsigned int l01 = (fbits(r0) >> 16) | (fbits(r1) & 0xFFFF0000u);
      unsigned int l23 = (fbits(r2) >> 16) | (fbits(r3) & 0xFFFF0000u);
      *(uint2*)&u.s.Bh[byte] = make_uint2(h01, h23);
      *(uint2*)&u.s.Bl[byte] = make_uint2(l01, l23);
    }
    __syncthreads();

    bf16x8 ah[4], al[4];
#pragma unroll
    for (int i = 0; i < 4; ++i) {
      int ab = frag32(wr * 4 + i, l);
      ah[i] = *(const bf16x8*)&u.s.Ah[ab];
      al[i] = *(const bf16x8*)&u.s.Al[ab];
    }
#pragma unroll
    for (int j = 0; j < 4; ++j) {
      int bb = frag32(wc * 4 + j, l);
      bf16x8 bh = *(const bf16x8*)&u.s.Bh[bb];
      bf16x8 bl = *(const bf16x8*)&u.s.Bl[bb];
#pragma unroll
      for (int i = 0; i < 4; ++i) {
        acc[i][j] = __builtin_amdgcn_mfma_f32_16x16x32_bf16(al[i], bh, acc[i][j], 0, 0, 0);
        acc[i][j] = __builtin_amdgcn_mfma_f32_16x16x32_bf16(ah[i], bl, acc[i][j], 0, 0, 0);
        acc[i][j] = __builtin_amdgcn_mfma_f32_16x16x32_bf16(ah[i], bh, acc[i][j], 0, 0, 0);
      }
    }
    __syncthreads();
  }

  // E write: gemm_wp's exact 2-pass LDS bounce -> coalesced float4 stores
  const int g = l >> 4, li = l & 15;
#pragma unroll
  for (int pass = 0; pass < 2; ++pass) {
    if (wr == pass) {
#pragma unroll
      for (int i = 0; i < 4; ++i)
#pragma unroll
        for (int j = 0; j < 4; ++j)
#pragma unroll
          for (int r = 0; r < 4; ++r)
            u.ep[i * 16 + g * 4 + r][wc * 64 + j * 16 + li] = acc[i][j][r];
    }
    __syncthreads();
#pragma unroll
    for (int i = 0; i < 8; ++i) {
      int idx = i * 256 + t;
      int r = idx >> 5, c4 = idx & 31;
      int grow = row0 + pass * 64 + r;
      float4 v = *(const float4*)&u.ep[r][c4 * 4];
      *(float4*)&C[(size_t)grow * NN + col0 + c4 * 4] = v;
    }
    __syncthreads();
  }
}

// --- Kernel 2a: row stats (softmax over h) — full reduction, no partials ----
__global__ __launch_bounds__(512) void row_stats(
    const float* __restrict__ e, const int* __restrict__ h_mask,
    float* __restrict__ rmax, float* __restrict__ rinv) {
  const int b = blockIdx.x, oct = blockIdx.y;
  __shared__ int hm[512];
  const int t = threadIdx.x;
  if (t < 128) *(int4*)&hm[t * 4] = *(const int4*)&h_mask[(size_t)b * NN + t * 4];
  __syncthreads();
  const int row = oct * 64 + (t >> 3), seg = t & 7;
  const float* er = e + (size_t)b * NN * NN + (size_t)row * NN + seg * 64;
  float m = -INFINITY, s = 0.f;
#pragma unroll
  for (int i = 0; i < 16; ++i) {
    float4 f = *(const float4*)&er[i * 4];
    int4 msk = *(const int4*)&hm[seg * 64 + i * 4];
    float vv[4] = {f.x, f.y, f.z, f.w};
    int mk[4] = {msk.x, msk.y, msk.z, msk.w};
#pragma unroll
    for (int c = 0; c < 4; ++c) {
      if (!mk[c]) {
        float mn = fmaxf(m, vv[c]);
        s = s * __expf(m - mn) + __expf(vv[c] - mn);
        m = mn;
      }
    }
  }
#pragma unroll
  for (int o = 1; o < 8; o <<= 1) {
    float m2 = __shfl_xor(m, o), s2 = __shfl_xor(s, o);
    float mn = fmaxf(m, m2);
    float sn = 0.f;
    if (s > 0.f) sn += s * __expf(m - mn);
    if (s2 > 0.f) sn += s2 * __expf(m2 - mn);
    m = mn; s = sn;
  }
  if (seg == 0) {
    rmax[(size_t)b * NN + row] = m;
    rinv[(size_t)b * NN + row] = 1.0f / s;
  }
}

// --- Kernel 2b: col stats (softmax over p) — full reduction, no partials ----
__global__ __launch_bounds__(512) void col_stats(
    const float* __restrict__ e, const int* __restrict__ p_mask,
    float* __restrict__ cmax, float* __restrict__ cinv) {
  const int b = blockIdx.x, oct = blockIdx.y;
  __shared__ int pm[512];
  const int t = threadIdx.x;
  if (t < 128) *(int4*)&pm[t * 4] = *(const int4*)&p_mask[(size_t)b * NN + t * 4];
  __syncthreads();
  const int col = oct * 64 + (t >> 3), seg = t & 7;
  const float* ec = e + (size_t)b * NN * NN + col;
  float m = -INFINITY, s = 0.f;
#pragma unroll 8
  for (int i = 0; i < 64; ++i) {
    int p = seg * 64 + i;
    if (!pm[p]) {
      float v = ec[(size_t)p * NN];
      float mn = fmaxf(m, v);
      s = s * __expf(m - mn) + __expf(v - mn);
      m = mn;
    }
  }
#pragma unroll
  for (int o = 1; o < 8; o <<= 1) {
    float m2 = __shfl_xor(m, o), s2 = __shfl_xor(s, o);
    float mn = fmaxf(m, m2);
    float sn = 0.f;
    if (s > 0.f) sn += s * __expf(m - mn);
    if (s2 > 0.f) sn += s2 * __expf(m2 - mn);
    m = mn; s = sn;
  }
  if (seg == 0) {
    cmax[(size_t)b * NN + col] = m;
    cinv[(size_t)b * NN + col] = 1.0f / s;
  }
}

// --- Kernel 3: m_p : px_hat = softmax_h(e) @ hx, weights computed on the fly
__global__ __launch_bounds__(256) void gemm_wp(
    const float* __restrict__ E, const float* __restrict__ hxg,
    const float* __restrict__ pxg, const int* __restrict__ h_mask,
    const float* __restrict__ rmax, const float* __restrict__ rinv,
    float* __restrict__ outg) {
  __shared__ union {
    struct { char A[16384]; char B[16384]; } s;
    float ep[64][132];
  } u;
  const int b = blockIdx.z;
  const float* Eb = E + (size_t)b * NN * NN;
  const float* B = hxg + (size_t)b * NN * NN;
  const float* X = pxg + (size_t)b * NN * NN;
  const int* hm = h_mask + (size_t)b * NN;
  const float* rmx = rmax + (size_t)b * NN;
  const float* rin = rinv + (size_t)b * NN;
  float* out = outg + (size_t)b * NN * ROWC;
  const int row0 = blockIdx.y * 128, col0 = blockIdx.x * 128;
  const int t = threadIdx.x;
  const int l = t & 63, w = t >> 6;
  const int wr = w >> 1, wc = w & 1;

  float rmv[8];
#pragma unroll
  for (int i = 0; i < 8; ++i) rmv[i] = rmx[row0 + ((i * 256 + t) >> 4)];

  f32x4 acc[4][4];
#pragma unroll
  for (int i = 0; i < 4; ++i)
#pragma unroll
    for (int j = 0; j < 4; ++j)
#pragma unroll
      for (int r = 0; r < 4; ++r) acc[i][j][r] = 0.f;

  for (int k0 = 0; k0 < NN; k0 += 64) {
    // stage A: w = exp(e - rowmax), masked h -> 0, to bf16 frag order
#pragma unroll
    for (int i = 0; i < 8; ++i) {
      int idx = i * 256 + t;
      int r = idx >> 4, c4 = idx & 15, k = c4 << 2;
      float4 f = *(const float4*)&Eb[(size_t)(row0 + r) * NN + k0 + k];
      int4 m4 = *(const int4*)&hm[k0 + k];
      float w0 = m4.x ? 0.f : __expf(f.x - rmv[i]);
      float w1 = m4.y ? 0.f : __expf(f.y - rmv[i]);
      float w2 = m4.z ? 0.f : __expf(f.z - rmv[i]);
      float w3 = m4.w ? 0.f : __expf(f.w - rmv[i]);
      unsigned int p01 = bf16_rne(w0) | (bf16_rne(w1) << 16);
      unsigned int p23 = bf16_rne(w2) | (bf16_rne(w3) << 16);
      int khalf = k >> 5, k8 = (k >> 3) & 3, j = k & 7;
      int byte = frag_byte(r >> 4, (r & 15) + (k8 << 4), khalf) + (j << 1);
      *(uint2*)&u.s.A[byte] = make_uint2(p01, p23);
    }
    // stage B: hx fp32 [k][n] -> bf16, transposed into frag order (k-pairs)
#pragma unroll
    for (int i = 0; i < 4; ++i) {
      int idx = i * 256 + t;
      int kp = idx >> 5, nq = idx & 31;
      int k = kp << 1, n = nq << 2;
      const float* p0 = &B[(size_t)(k0 + k) * NN + col0 + n];
      float4 f0 = *(const float4*)p0;
      float4 f1 = *(const float4*)(p0 + NN);
      int khalf = k >> 5, k8 = (k >> 3) & 3, j = k & 7;
      float fa0[4] = {f0.x, f0.y, f0.z, f0.w};
      float fa1[4] = {f1.x, f1.y, f1.z, f1.w};
#pragma unroll
      for (int c = 0; c < 4; ++c) {
        unsigned int pk = bf16_rne(fa0[c]) | (bf16_rne(fa1[c]) << 16);
        int nn2 = n + c;
        int byte = frag_byte(nn2 >> 4, (nn2 & 15) + (k8 << 4), khalf) + (j << 1);
        *(unsigned int*)&u.s.B[byte] = pk;
      }
    }
    __syncthreads();
#pragma unroll
    for (int kh = 0; kh < 2; ++kh) {
      bf16x8 av[4], bv[4];
#pragma unroll
      for (int i = 0; i < 4; ++i) {
        av[i] = *(const bf16x8*)&u.s.A[frag_byte(wr * 4 + i, l, kh)];
        bv[i] = *(const bf16x8*)&u.s.B[frag_byte(wc * 4 + i, l, kh)];
      }
#pragma unroll
      for (int i = 0; i < 4; ++i)
#pragma unroll
        for (int j = 0; j < 4; ++j)
          acc[i][j] = __builtin_amdgcn_mfma_f32_16x16x32_bf16(av[i], bv[j], acc[i][j], 0, 0, 0);
    }
    __syncthreads();
  }

  const int g = l >> 4, li = l & 15;
#pragma unroll
  for (int pass = 0; pass < 2; ++pass) {
    if (wr == pass) {
#pragma unroll
      for (int i = 0; i < 4; ++i)
#pragma unroll
        for (int j = 0; j < 4; ++j)
#pragma unroll
          for (int r = 0; r < 4; ++r)
            u.ep[i * 16 + g * 4 + r][wc * 64 + j * 16 + li] = acc[i][j][r];
    }
    __syncthreads();
#pragma unroll
    for (int i = 0; i < 8; ++i) {
      int idx = i * 256 + t;
      int r = idx >> 5, c4 = idx & 31;
      int grow = row0 + pass * 64 + r;
      float ri = rin[grow];
      float4 ph = *(const float4*)&u.ep[r][c4 * 4];
      ph.x *= ri; ph.y *= ri; ph.z *= ri; ph.w *= ri;
      float4 xv = *(const float4*)&X[(size_t)grow * NN + col0 + c4 * 4];
      size_t base = (size_t)grow * ROWC + col0 + c4 * 4;
      *(float4*)&out[base] = xv;
      *(float4*)&out[base + 512] = ph;
      float4 df = {xv.x - ph.x, xv.y - ph.y, xv.z - ph.z, xv.w - ph.w};
      *(float4*)&out[base + 1024] = df;
      float4 pr = {xv.x * ph.x, xv.y * ph.y, xv.z * ph.z, xv.w * ph.w};
      *(float4*)&out[base + 1536] = pr;
    }
    __syncthreads();
  }
}

// --- Kernel 4: m_h : hx_hat = softmax_p(e)^T @ px, weights on the fly ------
__global__ __launch_bounds__(256) void gemm_wh(
    const float* __restrict__ E, const float* __restrict__ pxg,
    const float* __restrict__ hxg, const int* __restrict__ p_mask,
    const float* __restrict__ cmax, const float* __restrict__ cinv,
    float* __restrict__ outg) {
  __shared__ union {
    struct { char A[16384]; char B[16384]; } s;
    float ep[64][132];
  } u;
  const int b = blockIdx.z;
  const float* Eb = E + (size_t)b * NN * NN;
  const float* B = pxg + (size_t)b * NN * NN;
  const float* X = hxg + (size_t)b * NN * NN;
  const int* pmsk = p_mask + (size_t)b * NN;
  const float* cmx = cmax + (size_t)b * NN;
  const float* cin = cinv + (size_t)b * NN;
  float* out = outg + (size_t)b * NN * ROWC;
  const int row0 = blockIdx.y * 128, col0 = blockIdx.x * 128;  // rows = h
  const int t = threadIdx.x;
  const int l = t & 63, w = t >> 6;
  const int wr = w >> 1, wc = w & 1;

  float4 cmv[4];
#pragma unroll
  for (int i = 0; i < 4; ++i) {
    int idx = i * 256 + t;
    int n = (idx & 31) << 2;
    cmv[i] = *(const float4*)&cmx[row0 + n];
  }

  f32x4 acc[4][4];
#pragma unroll
  for (int i = 0; i < 4; ++i)
#pragma unroll
    for (int j = 0; j < 4; ++j)
#pragma unroll
      for (int r = 0; r < 4; ++r) acc[i][j][r] = 0.f;

  for (int k0 = 0; k0 < NN; k0 += 64) {
    // stage A: w[h][p] = exp(e[p][h] - colmax[h]), masked p -> 0 (k-pairs)
#pragma unroll
    for (int i = 0; i < 4; ++i) {
      int idx = i * 256 + t;
      int kp = idx >> 5, nq = idx & 31;
      int k = kp << 1, n = nq << 2;
      const float* p0 = &Eb[(size_t)(k0 + k) * NN + row0 + n];
      float4 f0 = *(const float4*)p0;
      float4 f1 = *(const float4*)(p0 + NN);
      int pm0 = pmsk[k0 + k], pm1 = pmsk[k0 + k + 1];
      float fa0[4] = {f0.x, f0.y, f0.z, f0.w};
      float fa1[4] = {f1.x, f1.y, f1.z, f1.w};
      float cma[4] = {cmv[i].x, cmv[i].y, cmv[i].z, cmv[i].w};
      int khalf = k >> 5, k8 = (k >> 3) & 3, j = k & 7;
#pragma unroll
      for (int c = 0; c < 4; ++c) {
        float w0 = pm0 ? 0.f : __expf(fa0[c] - cma[c]);
        float w1 = pm1 ? 0.f : __expf(fa1[c] - cma[c]);
        unsigned int pk = bf16_rne(w0) | (bf16_rne(w1) << 16);
        int nn2 = n + c;
        int byte = frag_byte(nn2 >> 4, (nn2 & 15) + (k8 << 4), khalf) + (j << 1);
        *(unsigned int*)&u.s.A[byte] = pk;
      }
    }
    // stage B: px fp32 [k][n] -> bf16 frag order (k-pairs)
#pragma unroll
    for (int i = 0; i < 4; ++i) {
      int idx = i * 256 + t;
      int kp = idx >> 5, nq = idx & 31;
      int k = kp << 1, n = nq << 2;
      const float* p0 = &B[(size_t)(k0 + k) * NN + col0 + n];
      float4 f0 = *(const float4*)p0;
      float4 f1 = *(const float4*)(p0 + NN);
      int khalf = k >> 5, k8 = (k >> 3) & 3, j = k & 7;
      float fa0[4] = {f0.x, f0.y, f0.z, f0.w};
      float fa1[4] = {f1.x, f1.y, f1.z, f1.w};
#pragma unroll
      for (int c = 0; c < 4; ++c) {
        unsigned int pk = bf16_rne(fa0[c]) | (bf16_rne(fa1[c]) << 16);
        int nn2 = n + c;
        int byte = frag_byte(nn2 >> 4, (nn2 & 15) + (k8 << 4), khalf) + (j << 1);
        *(unsigned int*)&u.s.B[byte] = pk;
      }
    }
    __syncthreads();
#pragma unroll
    for (int kh = 0; kh < 2; ++kh) {
      bf16x8 av[4], bv[4];
#pragma unroll
      for (int i = 0; i < 4; ++i) {
        av[i] = *(const bf16x8*)&u.s.A[frag_byte(wr * 4 + i, l, kh)];
        bv[i] = *(const bf16x8*)&u.s.B[frag_byte(wc * 4 + i, l, kh)];
      }
#pragma unroll
      for (int i = 0; i < 4; ++i)
#pragma unroll
        for (int j = 0; j < 4; ++j)
          acc[i][j] = __builtin_amdgcn_mfma_f32_16x16x32_bf16(av[i], bv[j], acc[i][j], 0, 0, 0);
    }
    __syncthreads();
  }

  const int g = l >> 4, li = l & 15;
#pragma unroll
  for (int pass = 0; pass < 2; ++pass) {
    if (wr == pass) {
#pragma unroll
      for (int i = 0; i < 4; ++i)
#pragma unroll
        for (int j = 0; j < 4; ++j)
#pragma unroll
          for (int r = 0; r < 4; ++r)
            u.ep[i * 16 + g * 4 + r][wc * 64 + j * 16 + li] = acc[i][j][r];
    }
    __syncthreads();
#pragma unroll
    for (int i = 0; i < 8; ++i) {
      int idx = i * 256 + t;
      int r = idx >> 5, c4 = idx & 31;
      int grow = row0 + pass * 64 + r;  // h
      float ci = cin[grow];
      float4 hh = *(const float4*)&u.ep[r][c4 * 4];
      hh.x *= ci; hh.y *= ci; hh.z *= ci; hh.w *= ci;
      float4 xv = *(const float4*)&X[(size_t)grow * NN + col0 + c4 * 4];
      size_t base = (size_t)grow * ROWC + col0 + c4 * 4;
      *(float4*)&out[base] = xv;
      *(float4*)&out[base + 512] = hh;
      float4 df = {xv.x - hh.x, xv.y - hh.y, xv.z - hh.z, xv.w - hh.w};
      *(float4*)&out[base + 1024] = df;
      float4 pr = {xv.x * hh.x, xv.y * hh.y, xv.z * hh.z, xv.w * hh.w};
      *(float4*)&out[base + 1536] = pr;
    }
    __syncthreads();
  }
}

extern "C" void kernel_launch(void* const* d_in, const int* in_sizes, int n_in,
                              void* d_out, int out_size, void* d_ws, size_t ws_size,
                              hipStream_t stream) {
  const float* px = (const float*)d_in[0];
  const float* hx = (const float*)d_in[1];
  const int* p_mask = (const int*)d_in[2];
  const int* h_mask = (const int*)d_in[3];
  float* out = (float*)d_out;

  float* E = (float*)d_ws;                         // 33.5 MB fp32
  float* rmaxv = E + (size_t)NB * NN * NN;         // [B][NN] finals
  float* rinvv = rmaxv + (size_t)NB * NN;
  float* cmaxv = rinvv + (size_t)NB * NN;
  float* cinvv = cmaxv + (size_t)NB * NN;

  dim3 gg(4, 4, NB);
  gemm_e<<<gg, dim3(256), 0, stream>>>(px, hx, E);
  row_stats<<<dim3(NB, 8), dim3(512), 0, stream>>>(E, h_mask, rmaxv, rinvv);
  col_stats<<<dim3(NB, 8), dim3(512), 0, stream>>>(E, p_mask, cmaxv, cinvv);
  gemm_wp<<<gg, dim3(256), 0, stream>>>(E, hx, px, h_mask, rmaxv, rinvv, out);
  gemm_wh<<<gg, dim3(256), 0, stream>>>(E, px, hx, p_mask, cmaxv, cinvv,
                                        out + (size_t)NB * NN * ROWC);
}

// Round 12
// 232.754 us; speedup vs baseline: 1.0614x; 1.0614x over previous
//
#include <hip/hip_runtime.h>
#include <math.h>

#define NB 32
#define NN 512
#define ROWC 2048ull

typedef __attribute__((ext_vector_type(8))) short bf16x8;
typedef __attribute__((ext_vector_type(4))) float f32x4;

__device__ __forceinline__ unsigned int fbits(float f) {
  union { float f; unsigned int u; } v; v.f = f; return v.u;
}
__device__ __forceinline__ float bcast(unsigned int u) {
  union { unsigned int u; float f; } v; v.u = u; return v.f;
}
// round-to-nearest-even bf16, returned in low 16 bits
__device__ __forceinline__ unsigned int bf16_rne(float f) {
  unsigned int b = fbits(f);
  return (b + 0x7FFFu + ((b >> 16) & 1u)) >> 16;
}

// Build hi (truncated) + lo (truncated residual) bf16x8 fragments from 8 fp32.
// Same arithmetic as r2-r11 (verified absmax 0.125).
__device__ __forceinline__ void frag_hilo(float4 f0, float4 f1,
                                          bf16x8& hi, bf16x8& lo) {
  float f[8] = {f0.x, f0.y, f0.z, f0.w, f1.x, f1.y, f1.z, f1.w};
#pragma unroll
  for (int q = 0; q < 8; ++q) {
    unsigned int bq = fbits(f[q]);
    hi[q] = (short)(bq >> 16);
    float r = f[q] - bcast(bq & 0xFFFF0000u);
    lo[q] = (short)(fbits(r) >> 16);
  }
}

// Fragment-ordered LDS address (BK=64 form) used by gemm_wp / gemm_wh.
__device__ __forceinline__ int frag_byte(int blk, int lane, int khalf) {
  int base = ((((khalf << 3) + blk) << 6) + lane) << 4;
  int swz = (blk ^ (lane >> 4) ^ (khalf << 2)) & 7;
  return base ^ (swz << 4);
}

// --- Kernel 1: e = px.hx^T, 3-term split bf16, REGISTER-DIRECT fragments ----
// No LDS, no barriers in the k-loop: lane l loads its MFMA fragment straight
// from global (A[row0+blk*16+(l&15)][k0+(l>>4)*8..+8] = 2 float4, 128B-
// contiguous per row across the wave), converts to hi/lo in registers.
// Rationale: r7 measured 21.8M LDS-conflict cycles; hi/lo split doubles LDS
// traffic; every frag map lands ~8-way on ds_read_b128. Remove the pipe.
__global__ __launch_bounds__(256) void gemm_e(
    const float* __restrict__ px, const float* __restrict__ hx,
    float* __restrict__ e) {
  __shared__ float ep[64][132];
  const int b = blockIdx.z;
  const float* A = px + (size_t)b * NN * NN;
  const float* B = hx + (size_t)b * NN * NN;
  float* C = e + (size_t)b * NN * NN;
  const int row0 = blockIdx.y * 128, col0 = blockIdx.x * 128;
  const int t = threadIdx.x;
  const int l = t & 63, w = t >> 6;
  const int wr = w >> 1, wc = w & 1;
  const int fr = l & 15, fk = (l >> 4) * 8;

  f32x4 acc[4][4];
#pragma unroll
  for (int i = 0; i < 4; ++i)
#pragma unroll
    for (int j = 0; j < 4; ++j)
#pragma unroll
      for (int r = 0; r < 4; ++r) acc[i][j][r] = 0.f;

  const float* pa[4];
  const float* pb[4];
#pragma unroll
  for (int i = 0; i < 4; ++i)
    pa[i] = A + (size_t)(row0 + wr * 64 + i * 16 + fr) * NN + fk;
#pragma unroll
  for (int j = 0; j < 4; ++j)
    pb[j] = B + (size_t)(col0 + wc * 64 + j * 16 + fr) * NN + fk;

  for (int k0 = 0; k0 < NN; k0 += 32) {
    bf16x8 ah[4], al[4];
#pragma unroll
    for (int i = 0; i < 4; ++i) {
      float4 f0 = *(const float4*)(pa[i] + k0);
      float4 f1 = *(const float4*)(pa[i] + k0 + 4);
      frag_hilo(f0, f1, ah[i], al[i]);
    }
#pragma unroll
    for (int j = 0; j < 4; ++j) {
      float4 g0 = *(const float4*)(pb[j] + k0);
      float4 g1 = *(const float4*)(pb[j] + k0 + 4);
      bf16x8 bh, bl;
      frag_hilo(g0, g1, bh, bl);
#pragma unroll
      for (int i = 0; i < 4; ++i)
        acc[i][j] = __builtin_amdgcn_mfma_f32_16x16x32_bf16(al[i], bh, acc[i][j], 0, 0, 0);
#pragma unroll
      for (int i = 0; i < 4; ++i)
        acc[i][j] = __builtin_amdgcn_mfma_f32_16x16x32_bf16(ah[i], bl, acc[i][j], 0, 0, 0);
#pragma unroll
      for (int i = 0; i < 4; ++i)
        acc[i][j] = __builtin_amdgcn_mfma_f32_16x16x32_bf16(ah[i], bh, acc[i][j], 0, 0, 0);
    }
  }

  // E write: 2-pass LDS bounce -> coalesced float4 stores (wp's epilogue)
  const int g = l >> 4, li = l & 15;
#pragma unroll
  for (int pass = 0; pass < 2; ++pass) {
    if (wr == pass) {
#pragma unroll
      for (int i = 0; i < 4; ++i)
#pragma unroll
        for (int j = 0; j < 4; ++j)
#pragma unroll
          for (int r = 0; r < 4; ++r)
            ep[i * 16 + g * 4 + r][wc * 64 + j * 16 + li] = acc[i][j][r];
    }
    __syncthreads();
#pragma unroll
    for (int i = 0; i < 8; ++i) {
      int idx = i * 256 + t;
      int r = idx >> 5, c4 = idx & 31;
      int grow = row0 + pass * 64 + r;
      float4 v = *(const float4*)&ep[r][c4 * 4];
      *(float4*)&C[(size_t)grow * NN + col0 + c4 * 4] = v;
    }
    __syncthreads();
  }
}

// --- Kernel 2a: row stats (softmax over h) — full reduction, no partials ----
__global__ __launch_bounds__(512) void row_stats(
    const float* __restrict__ e, const int* __restrict__ h_mask,
    float* __restrict__ rmax, float* __restrict__ rinv) {
  const int b = blockIdx.x, oct = blockIdx.y;
  __shared__ int hm[512];
  const int t = threadIdx.x;
  if (t < 128) *(int4*)&hm[t * 4] = *(const int4*)&h_mask[(size_t)b * NN + t * 4];
  __syncthreads();
  const int row = oct * 64 + (t >> 3), seg = t & 7;
  const float* er = e + (size_t)b * NN * NN + (size_t)row * NN + seg * 64;
  float m = -INFINITY, s = 0.f;
#pragma unroll
  for (int i = 0; i < 16; ++i) {
    float4 f = *(const float4*)&er[i * 4];
    int4 msk = *(const int4*)&hm[seg * 64 + i * 4];
    float vv[4] = {f.x, f.y, f.z, f.w};
    int mk[4] = {msk.x, msk.y, msk.z, msk.w};
#pragma unroll
    for (int c = 0; c < 4; ++c) {
      if (!mk[c]) {
        float mn = fmaxf(m, vv[c]);
        s = s * __expf(m - mn) + __expf(vv[c] - mn);
        m = mn;
      }
    }
  }
#pragma unroll
  for (int o = 1; o < 8; o <<= 1) {
    float m2 = __shfl_xor(m, o), s2 = __shfl_xor(s, o);
    float mn = fmaxf(m, m2);
    float sn = 0.f;
    if (s > 0.f) sn += s * __expf(m - mn);
    if (s2 > 0.f) sn += s2 * __expf(m2 - mn);
    m = mn; s = sn;
  }
  if (seg == 0) {
    rmax[(size_t)b * NN + row] = m;
    rinv[(size_t)b * NN + row] = 1.0f / s;
  }
}

// --- Kernel 2b: col stats (softmax over p) — full reduction, no partials ----
__global__ __launch_bounds__(512) void col_stats(
    const float* __restrict__ e, const int* __restrict__ p_mask,
    float* __restrict__ cmax, float* __restrict__ cinv) {
  const int b = blockIdx.x, oct = blockIdx.y;
  __shared__ int pm[512];
  const int t = threadIdx.x;
  if (t < 128) *(int4*)&pm[t * 4] = *(const int4*)&p_mask[(size_t)b * NN + t * 4];
  __syncthreads();
  const int col = oct * 64 + (t >> 3), seg = t & 7;
  const float* ec = e + (size_t)b * NN * NN + col;
  float m = -INFINITY, s = 0.f;
#pragma unroll 8
  for (int i = 0; i < 64; ++i) {
    int p = seg * 64 + i;
    if (!pm[p]) {
      float v = ec[(size_t)p * NN];
      float mn = fmaxf(m, v);
      s = s * __expf(m - mn) + __expf(v - mn);
      m = mn;
    }
  }
#pragma unroll
  for (int o = 1; o < 8; o <<= 1) {
    float m2 = __shfl_xor(m, o), s2 = __shfl_xor(s, o);
    float mn = fmaxf(m, m2);
    float sn = 0.f;
    if (s > 0.f) sn += s * __expf(m - mn);
    if (s2 > 0.f) sn += s2 * __expf(m2 - mn);
    m = mn; s = sn;
  }
  if (seg == 0) {
    cmax[(size_t)b * NN + col] = m;
    cinv[(size_t)b * NN + col] = 1.0f / s;
  }
}

// --- Kernel 3: m_p : px_hat = softmax_h(e) @ hx, weights computed on the fly
__global__ __launch_bounds__(256) void gemm_wp(
    const float* __restrict__ E, const float* __restrict__ hxg,
    const float* __restrict__ pxg, const int* __restrict__ h_mask,
    const float* __restrict__ rmax, const float* __restrict__ rinv,
    float* __restrict__ outg) {
  __shared__ union {
    struct { char A[16384]; char B[16384]; } s;
    float ep[64][132];
  } u;
  const int b = blockIdx.z;
  const float* Eb = E + (size_t)b * NN * NN;
  const float* B = hxg + (size_t)b * NN * NN;
  const float* X = pxg + (size_t)b * NN * NN;
  const int* hm = h_mask + (size_t)b * NN;
  const float* rmx = rmax + (size_t)b * NN;
  const float* rin = rinv + (size_t)b * NN;
  float* out = outg + (size_t)b * NN * ROWC;
  const int row0 = blockIdx.y * 128, col0 = blockIdx.x * 128;
  const int t = threadIdx.x;
  const int l = t & 63, w = t >> 6;
  const int wr = w >> 1, wc = w & 1;

  float rmv[8];
#pragma unroll
  for (int i = 0; i < 8; ++i) rmv[i] = rmx[row0 + ((i * 256 + t) >> 4)];

  f32x4 acc[4][4];
#pragma unroll
  for (int i = 0; i < 4; ++i)
#pragma unroll
    for (int j = 0; j < 4; ++j)
#pragma unroll
      for (int r = 0; r < 4; ++r) acc[i][j][r] = 0.f;

  for (int k0 = 0; k0 < NN; k0 += 64) {
    // stage A: w = exp(e - rowmax), masked h -> 0, to bf16 frag order
#pragma unroll
    for (int i = 0; i < 8; ++i) {
      int idx = i * 256 + t;
      int r = idx >> 4, c4 = idx & 15, k = c4 << 2;
      float4 f = *(const float4*)&Eb[(size_t)(row0 + r) * NN + k0 + k];
      int4 m4 = *(const int4*)&hm[k0 + k];
      float w0 = m4.x ? 0.f : __expf(f.x - rmv[i]);
      float w1 = m4.y ? 0.f : __expf(f.y - rmv[i]);
      float w2 = m4.z ? 0.f : __expf(f.z - rmv[i]);
      float w3 = m4.w ? 0.f : __expf(f.w - rmv[i]);
      unsigned int p01 = bf16_rne(w0) | (bf16_rne(w1) << 16);
      unsigned int p23 = bf16_rne(w2) | (bf16_rne(w3) << 16);
      int khalf = k >> 5, k8 = (k >> 3) & 3, j = k & 7;
      int byte = frag_byte(r >> 4, (r & 15) + (k8 << 4), khalf) + (j << 1);
      *(uint2*)&u.s.A[byte] = make_uint2(p01, p23);
    }
    // stage B: hx fp32 [k][n] -> bf16, transposed into frag order (k-pairs)
#pragma unroll
    for (int i = 0; i < 4; ++i) {
      int idx = i * 256 + t;
      int kp = idx >> 5, nq = idx & 31;
      int k = kp << 1, n = nq << 2;
      const float* p0 = &B[(size_t)(k0 + k) * NN + col0 + n];
      float4 f0 = *(const float4*)p0;
      float4 f1 = *(const float4*)(p0 + NN);
      int khalf = k >> 5, k8 = (k >> 3) & 3, j = k & 7;
      float fa0[4] = {f0.x, f0.y, f0.z, f0.w};
      float fa1[4] = {f1.x, f1.y, f1.z, f1.w};
#pragma unroll
      for (int c = 0; c < 4; ++c) {
        unsigned int pk = bf16_rne(fa0[c]) | (bf16_rne(fa1[c]) << 16);
        int nn2 = n + c;
        int byte = frag_byte(nn2 >> 4, (nn2 & 15) + (k8 << 4), khalf) + (j << 1);
        *(unsigned int*)&u.s.B[byte] = pk;
      }
    }
    __syncthreads();
#pragma unroll
    for (int kh = 0; kh < 2; ++kh) {
      bf16x8 av[4], bv[4];
#pragma unroll
      for (int i = 0; i < 4; ++i) {
        av[i] = *(const bf16x8*)&u.s.A[frag_byte(wr * 4 + i, l, kh)];
        bv[i] = *(const bf16x8*)&u.s.B[frag_byte(wc * 4 + i, l, kh)];
      }
#pragma unroll
      for (int i = 0; i < 4; ++i)
#pragma unroll
        for (int j = 0; j < 4; ++j)
          acc[i][j] = __builtin_amdgcn_mfma_f32_16x16x32_bf16(av[i], bv[j], acc[i][j], 0, 0, 0);
    }
    __syncthreads();
  }

  const int g = l >> 4, li = l & 15;
#pragma unroll
  for (int pass = 0; pass < 2; ++pass) {
    if (wr == pass) {
#pragma unroll
      for (int i = 0; i < 4; ++i)
#pragma unroll
        for (int j = 0; j < 4; ++j)
#pragma unroll
          for (int r = 0; r < 4; ++r)
            u.ep[i * 16 + g * 4 + r][wc * 64 + j * 16 + li] = acc[i][j][r];
    }
    __syncthreads();
#pragma unroll
    for (int i = 0; i < 8; ++i) {
      int idx = i * 256 + t;
      int r = idx >> 5, c4 = idx & 31;
      int grow = row0 + pass * 64 + r;
      float ri = rin[grow];
      float4 ph = *(const float4*)&u.ep[r][c4 * 4];
      ph.x *= ri; ph.y *= ri; ph.z *= ri; ph.w *= ri;
      float4 xv = *(const float4*)&X[(size_t)grow * NN + col0 + c4 * 4];
      size_t base = (size_t)grow * ROWC + col0 + c4 * 4;
      *(float4*)&out[base] = xv;
      *(float4*)&out[base + 512] = ph;
      float4 df = {xv.x - ph.x, xv.y - ph.y, xv.z - ph.z, xv.w - ph.w};
      *(float4*)&out[base + 1024] = df;
      float4 pr = {xv.x * ph.x, xv.y * ph.y, xv.z * ph.z, xv.w * ph.w};
      *(float4*)&out[base + 1536] = pr;
    }
    __syncthreads();
  }
}

// --- Kernel 4: m_h : hx_hat = softmax_p(e)^T @ px, weights on the fly ------
__global__ __launch_bounds__(256) void gemm_wh(
    const float* __restrict__ E, const float* __restrict__ pxg,
    const float* __restrict__ hxg, const int* __restrict__ p_mask,
    const float* __restrict__ cmax, const float* __restrict__ cinv,
    float* __restrict__ outg) {
  __shared__ union {
    struct { char A[16384]; char B[16384]; } s;
    float ep[64][132];
  } u;
  const int b = blockIdx.z;
  const float* Eb = E + (size_t)b * NN * NN;
  const float* B = pxg + (size_t)b * NN * NN;
  const float* X = hxg + (size_t)b * NN * NN;
  const int* pmsk = p_mask + (size_t)b * NN;
  const float* cmx = cmax + (size_t)b * NN;
  const float* cin = cinv + (size_t)b * NN;
  float* out = outg + (size_t)b * NN * ROWC;
  const int row0 = blockIdx.y * 128, col0 = blockIdx.x * 128;  // rows = h
  const int t = threadIdx.x;
  const int l = t & 63, w = t >> 6;
  const int wr = w >> 1, wc = w & 1;

  float4 cmv[4];
#pragma unroll
  for (int i = 0; i < 4; ++i) {
    int idx = i * 256 + t;
    int n = (idx & 31) << 2;
    cmv[i] = *(const float4*)&cmx[row0 + n];
  }

  f32x4 acc[4][4];
#pragma unroll
  for (int i = 0; i < 4; ++i)
#pragma unroll
    for (int j = 0; j < 4; ++j)
#pragma unroll
      for (int r = 0; r < 4; ++r) acc[i][j][r] = 0.f;

  for (int k0 = 0; k0 < NN; k0 += 64) {
    // stage A: w[h][p] = exp(e[p][h] - colmax[h]), masked p -> 0 (k-pairs)
#pragma unroll
    for (int i = 0; i < 4; ++i) {
      int idx = i * 256 + t;
      int kp = idx >> 5, nq = idx & 31;
      int k = kp << 1, n = nq << 2;
      const float* p0 = &Eb[(size_t)(k0 + k) * NN + row0 + n];
      float4 f0 = *(const float4*)p0;
      float4 f1 = *(const float4*)(p0 + NN);
      int pm0 = pmsk[k0 + k], pm1 = pmsk[k0 + k + 1];
      float fa0[4] = {f0.x, f0.y, f0.z, f0.w};
      float fa1[4] = {f1.x, f1.y, f1.z, f1.w};
      float cma[4] = {cmv[i].x, cmv[i].y, cmv[i].z, cmv[i].w};
      int khalf = k >> 5, k8 = (k >> 3) & 3, j = k & 7;
#pragma unroll
      for (int c = 0; c < 4; ++c) {
        float w0 = pm0 ? 0.f : __expf(fa0[c] - cma[c]);
        float w1 = pm1 ? 0.f : __expf(fa1[c] - cma[c]);
        unsigned int pk = bf16_rne(w0) | (bf16_rne(w1) << 16);
        int nn2 = n + c;
        int byte = frag_byte(nn2 >> 4, (nn2 & 15) + (k8 << 4), khalf) + (j << 1);
        *(unsigned int*)&u.s.A[byte] = pk;
      }
    }
    // stage B: px fp32 [k][n] -> bf16 frag order (k-pairs)
#pragma unroll
    for (int i = 0; i < 4; ++i) {
      int idx = i * 256 + t;
      int kp = idx >> 5, nq = idx & 31;
      int k = kp << 1, n = nq << 2;
      const float* p0 = &B[(size_t)(k0 + k) * NN + col0 + n];
      float4 f0 = *(const float4*)p0;
      float4 f1 = *(const float4*)(p0 + NN);
      int khalf = k >> 5, k8 = (k >> 3) & 3, j = k & 7;
      float fa0[4] = {f0.x, f0.y, f0.z, f0.w};
      float fa1[4] = {f1.x, f1.y, f1.z, f1.w};
#pragma unroll
      for (int c = 0; c < 4; ++c) {
        unsigned int pk = bf16_rne(fa0[c]) | (bf16_rne(fa1[c]) << 16);
        int nn2 = n + c;
        int byte = frag_byte(nn2 >> 4, (nn2 & 15) + (k8 << 4), khalf) + (j << 1);
        *(unsigned int*)&u.s.B[byte] = pk;
      }
    }
    __syncthreads();
#pragma unroll
    for (int kh = 0; kh < 2; ++kh) {
      bf16x8 av[4], bv[4];
#pragma unroll
      for (int i = 0; i < 4; ++i) {
        av[i] = *(const bf16x8*)&u.s.A[frag_byte(wr * 4 + i, l, kh)];
        bv[i] = *(const bf16x8*)&u.s.B[frag_byte(wc * 4 + i, l, kh)];
      }
#pragma unroll
      for (int i = 0; i < 4; ++i)
#pragma unroll
        for (int j = 0; j < 4; ++j)
          acc[i][j] = __builtin_amdgcn_mfma_f32_16x16x32_bf16(av[i], bv[j], acc[i][j], 0, 0, 0);
    }
    __syncthreads();
  }

  const int g = l >> 4, li = l & 15;
#pragma unroll
  for (int pass = 0; pass < 2; ++pass) {
    if (wr == pass) {
#pragma unroll
      for (int i = 0; i < 4; ++i)
#pragma unroll
        for (int j = 0; j < 4; ++j)
#pragma unroll
          for (int r = 0; r < 4; ++r)
            u.ep[i * 16 + g * 4 + r][wc * 64 + j * 16 + li] = acc[i][j][r];
    }
    __syncthreads();
#pragma unroll
    for (int i = 0; i < 8; ++i) {
      int idx = i * 256 + t;
      int r = idx >> 5, c4 = idx & 31;
      int grow = row0 + pass * 64 + r;  // h
      float ci = cin[grow];
      float4 hh = *(const float4*)&u.ep[r][c4 * 4];
      hh.x *= ci; hh.y *= ci; hh.z *= ci; hh.w *= ci;
      float4 xv = *(const float4*)&X[(size_t)grow * NN + col0 + c4 * 4];
      size_t base = (size_t)grow * ROWC + col0 + c4 * 4;
      *(float4*)&out[base] = xv;
      *(float4*)&out[base + 512] = hh;
      float4 df = {xv.x - hh.x, xv.y - hh.y, xv.z - hh.z, xv.w - hh.w};
      *(float4*)&out[base + 1024] = df;
      float4 pr = {xv.x * hh.x, xv.y * hh.y, xv.z * hh.z, xv.w * hh.w};
      *(float4*)&out[base + 1536] = pr;
    }
    __syncthreads();
  }
}

extern "C" void kernel_launch(void* const* d_in, const int* in_sizes, int n_in,
                              void* d_out, int out_size, void* d_ws, size_t ws_size,
                              hipStream_t stream) {
  const float* px = (const float*)d_in[0];
  const float* hx = (const float*)d_in[1];
  const int* p_mask = (const int*)d_in[2];
  const int* h_mask = (const int*)d_in[3];
  float* out = (float*)d_out;

  float* E = (float*)d_ws;                         // 33.5 MB fp32
  float* rmaxv = E + (size_t)NB * NN * NN;         // [B][NN] finals
  float* rinvv = rmaxv + (size_t)NB * NN;
  float* cmaxv = rinvv + (size_t)NB * NN;
  float* cinvv = cmaxv + (size_t)NB * NN;

  dim3 gg(4, 4, NB);
  gemm_e<<<gg, dim3(256), 0, stream>>>(px, hx, E);
  row_stats<<<dim3(NB, 8), dim3(512), 0, stream>>>(E, h_mask, rmaxv, rinvv);
  col_stats<<<dim3(NB, 8), dim3(512), 0, stream>>>(E, p_mask, cmaxv, cinvv);
  gemm_wp<<<gg, dim3(256), 0, stream>>>(E, hx, px, h_mask, rmaxv, rinvv, out);
  gemm_wh<<<gg, dim3(256), 0, stream>>>(E, px, hx, p_mask, cmaxv, cinvv,
                                        out + (size_t)NB * NN * ROWC);
}